// Round 1
// baseline (3199.787 us; speedup 1.0000x reference)
//
#include <hip/hip_runtime.h>

// LSTM_77893526880768: B=T=F=H=256.
// Reference: 255 sequential steps; h,c are (256,256); row r of h/c depends ONLY
// on row r of x and h  =>  256 independent LSTM chains.
//
// Plan:
//   prep_w:       transpose 8 fp32 256x256 weights -> WxT/WhT [1024][256] bf16 (n = gate*256+j)
//   prep_b:       bcat[n] = x-bias + h-bias (folded into P)
//   precompute:   P[t][n][r] = bcat[n] + sum_k x[r,t,k]*Wx[k,n]   (bf16, 255*1024*256)
//   recurrent:    16 WGs x 16 rows, 255 steps; per step each wave does a
//                 16x256 @ 256x256 bf16 MFMA slab (B streamed from L2-resident WhT),
//                 gates in fp32, c in registers, h through LDS (bf16).
//
// Workspace layout (needs ~135 MB):
//   [0, 512K)        WxT bf16
//   [512K, 1M)       WhT bf16
//   [1M, 1M+4K)      bcat fp32
//   [1M+4K, ...)     P bf16  (255*1024*256*2 = 133,693,440 B)

#define STEPS 255

typedef short bf16x8 __attribute__((ext_vector_type(8)));
typedef short bf16x4 __attribute__((ext_vector_type(4)));
typedef float f32x4  __attribute__((ext_vector_type(4)));

__device__ inline unsigned short f2bf(float f) {
  unsigned int u = __float_as_uint(f);
  unsigned int r = (u + 0x7FFFu + ((u >> 16) & 1u)) >> 16;  // RNE
  return (unsigned short)r;
}
__device__ inline float bf2f(unsigned short s) {
  return __uint_as_float(((unsigned int)s) << 16);
}
__device__ inline float sig_f(float x) {
  // sigmoid(x) = 1/(1+2^(-x*log2 e))
  float e = exp2f(-1.442695041f * x);
  return __builtin_amdgcn_rcpf(1.0f + e);
}
__device__ inline float tanh_f(float x) {
  // tanh(x) = 2/(1+2^(-2x*log2 e)) - 1
  float e = exp2f(-2.885390082f * x);
  return 2.0f * __builtin_amdgcn_rcpf(1.0f + e) - 1.0f;
}

// ---------- prep: W transpose (W[k][j] fp32 -> WT[g*256+j][k] bf16) ----------
__global__ __launch_bounds__(256) void lstm_prep_w(
    const float* __restrict__ m0, const float* __restrict__ m1,
    const float* __restrict__ m2, const float* __restrict__ m3,
    const float* __restrict__ m4, const float* __restrict__ m5,
    const float* __restrict__ m6, const float* __restrict__ m7,
    unsigned short* __restrict__ WxT, unsigned short* __restrict__ WhT) {
  const float* mats[8] = {m0, m1, m2, m3, m4, m5, m6, m7};
  int mat = blockIdx.z;                       // 0..3 = x-side gates, 4..7 = h-side
  const float* W = mats[mat];
  unsigned short* out = (mat < 4 ? WxT : WhT) + (size_t)(mat & 3) * 256 * 256;
  int kblk = blockIdx.x * 32, jblk = blockIdx.y * 32;
  __shared__ float tile[32][33];
  int tx = threadIdx.x & 31, ty = threadIdx.x >> 5;  // ty: 0..7
#pragma unroll
  for (int i = 0; i < 4; ++i) {
    int kk = ty + i * 8;
    tile[kk][tx] = W[(size_t)(kblk + kk) * 256 + jblk + tx];  // coalesced in j
  }
  __syncthreads();
#pragma unroll
  for (int i = 0; i < 4; ++i) {
    int jj = ty + i * 8;
    out[(size_t)(jblk + jj) * 256 + kblk + tx] = f2bf(tile[tx][jj]);  // coalesced in k
  }
}

// ---------- prep: bias fold ----------
__global__ void lstm_prep_b(
    const float* __restrict__ bx0, const float* __restrict__ bx1,
    const float* __restrict__ bx2, const float* __restrict__ bx3,
    const float* __restrict__ bh0, const float* __restrict__ bh1,
    const float* __restrict__ bh2, const float* __restrict__ bh3,
    float* __restrict__ bcat) {
  const float* bx[4] = {bx0, bx1, bx2, bx3};
  const float* bh[4] = {bh0, bh1, bh2, bh3};
  int i = blockIdx.x * 256 + threadIdx.x;  // grid 4 x 256
  int g = i >> 8, j = i & 255;
  bcat[i] = bx[g][j] + bh[g][j];
}

// ---------- precompute: P[t][n][r] = bcat[n] + sum_k x[r,t,k] Wx[k,n] ----------
// GEMM with M-dim = n (A = WxT, frags direct from global, 16B/lane)
//           N-dim = r (B = x, 8 consecutive fp32 per lane, cvt to bf16)
__global__ __launch_bounds__(256) void lstm_precompute(
    const float* __restrict__ x, const unsigned short* __restrict__ WxT,
    const float* __restrict__ bcat, unsigned short* __restrict__ P) {
  int t = blockIdx.x;           // 0..254
  int nblk = blockIdx.y * 64;   // 16 n-blocks
  int tid = threadIdx.x;
  int w = tid >> 6, lane = tid & 63, q = lane >> 4, cl = lane & 15;
  int rbase = w * 64;           // wave w -> r-slice of 64

  f32x4 acc[4][4];  // [mt(n)][rt(r)]
#pragma unroll
  for (int a = 0; a < 4; ++a)
#pragma unroll
    for (int b = 0; b < 4; ++b) acc[a][b] = f32x4{0.f, 0.f, 0.f, 0.f};

#pragma unroll
  for (int kt = 0; kt < 8; ++kt) {
    int k0 = kt * 32 + q * 8;
    bf16x8 bfrag[4];
#pragma unroll
    for (int rt = 0; rt < 4; ++rt) {
      const float* xp = x + (((size_t)(rbase + rt * 16 + cl) * 256 + t) * 256 + k0);
      f32x4 lo = *(const f32x4*)xp;
      f32x4 hi = *(const f32x4*)(xp + 4);
      bf16x8 bv;
      bv[0] = (short)f2bf(lo[0]); bv[1] = (short)f2bf(lo[1]);
      bv[2] = (short)f2bf(lo[2]); bv[3] = (short)f2bf(lo[3]);
      bv[4] = (short)f2bf(hi[0]); bv[5] = (short)f2bf(hi[1]);
      bv[6] = (short)f2bf(hi[2]); bv[7] = (short)f2bf(hi[3]);
      bfrag[rt] = bv;
    }
    bf16x8 afrag[4];
#pragma unroll
    for (int mt = 0; mt < 4; ++mt)
      afrag[mt] = *(const bf16x8*)(WxT + (size_t)(nblk + mt * 16 + cl) * 256 + k0);
#pragma unroll
    for (int mt = 0; mt < 4; ++mt)
#pragma unroll
      for (int rt = 0; rt < 4; ++rt)
        acc[mt][rt] = __builtin_amdgcn_mfma_f32_16x16x32_bf16(
            afrag[mt], bfrag[rt], acc[mt][rt], 0, 0, 0);
  }
  // epilogue: D row (= n) = q*4+reg, col (= r) = cl
#pragma unroll
  for (int mt = 0; mt < 4; ++mt) {
#pragma unroll
    for (int reg = 0; reg < 4; ++reg) {
      int n = nblk + mt * 16 + q * 4 + reg;
      float bb = bcat[n];
#pragma unroll
      for (int rt = 0; rt < 4; ++rt) {
        int r = rbase + rt * 16 + cl;
        P[((size_t)t * 1024 + n) * 256 + r] = f2bf(acc[mt][rt][reg] + bb);
      }
    }
  }
}

// ---------- recurrent: 16 WGs x 16 rows, 255 sequential steps ----------
// wave w owns hidden cols [w*64, w*64+64): computes all 4 gates for those cols,
// updates its c slice (fp32 regs) and writes h slice (bf16) to LDS for next step.
__global__ __launch_bounds__(256, 1) void lstm_recurrent(
    const unsigned short* __restrict__ WhT, const unsigned short* __restrict__ P,
    float* __restrict__ out) {
  __shared__ __align__(16) unsigned short hlds[16][264];  // +8 bf16 pad: 2-way LDS aliasing only
  int tid = threadIdx.x;
  int w = tid >> 6, lane = tid & 63, q = lane >> 4, cl = lane & 15;
  int r0 = blockIdx.x * 16;

  for (int i = tid; i < 16 * 264; i += 256) (&hlds[0][0])[i] = 0;  // h0 = 0

  float creg[4][4];  // c[r=q*4+reg][j=w*64+jt*16+cl], fp32 resident all 255 steps
#pragma unroll
  for (int jt = 0; jt < 4; ++jt)
#pragma unroll
    for (int rg = 0; rg < 4; ++rg) creg[jt][rg] = 0.0f;

  __syncthreads();

  for (int t = 0; t < STEPS; ++t) {
    // A-frags for this step's h (A[m=cl][k=q*8+j]) from LDS
    bf16x8 afrag[8];
#pragma unroll
    for (int kt = 0; kt < 8; ++kt)
      afrag[kt] = *(const bf16x8*)(&hlds[cl][kt * 32 + q * 8]);

    f32x4 acc[4][4];  // [gate][jt]
#pragma unroll
    for (int g = 0; g < 4; ++g)
#pragma unroll
      for (int jt = 0; jt < 4; ++jt) acc[g][jt] = f32x4{0.f, 0.f, 0.f, 0.f};

    // stream B (512 KB/WG/step from L2-resident WhT): 16 n-tiles x 8 k-tiles
#pragma unroll
    for (int g = 0; g < 4; ++g) {
#pragma unroll
      for (int jt = 0; jt < 4; ++jt) {
        const unsigned short* bp =
            WhT + (size_t)(g * 256 + w * 64 + jt * 16 + cl) * 256 + q * 8;
#pragma unroll
        for (int kt = 0; kt < 8; ++kt) {
          bf16x8 bfrag = *(const bf16x8*)(bp + kt * 32);
          acc[g][jt] = __builtin_amdgcn_mfma_f32_16x16x32_bf16(
              afrag[kt], bfrag, acc[g][jt], 0, 0, 0);
        }
      }
    }

    __syncthreads();  // all waves' afrag reads (pre-MFMA) are done -> safe to overwrite hlds

    const unsigned short* Pt = P + (size_t)t * 1024 * 256;
    bool last = (t == STEPS - 1);
#pragma unroll
    for (int jt = 0; jt < 4; ++jt) {
      int jcol = w * 64 + jt * 16 + cl;
      f32x4 pre[4];
#pragma unroll
      for (int g = 0; g < 4; ++g) {
        // P[t][n][r]: 4 consecutive r (rows q*4..q*4+3) = one 8B load
        bf16x4 pv = *(const bf16x4*)(Pt + (size_t)(g * 256 + jcol) * 256 + r0 + q * 4);
#pragma unroll
        for (int rg = 0; rg < 4; ++rg)
          pre[g][rg] = acc[g][jt][rg] + bf2f((unsigned short)pv[rg]);
      }
#pragma unroll
      for (int rg = 0; rg < 4; ++rg) {
        float ig = sig_f(pre[0][rg]);
        float fg = sig_f(pre[1][rg]);
        float gg = tanh_f(pre[2][rg]);
        float og = sig_f(pre[3][rg]);
        float cn = fg * creg[jt][rg] + ig * gg;
        creg[jt][rg] = cn;
        float hn = og * tanh_f(cn);
        hlds[q * 4 + rg][jcol] = f2bf(hn);
        if (last) {
          int r = r0 + q * 4 + rg;
          out[(size_t)r * 256 + jcol] = hn;            // h (fp32, pre-rounding)
          out[65536 + (size_t)r * 256 + jcol] = cn;    // c
        }
      }
    }
    __syncthreads();  // h_new fully in LDS before next step's afrag reads
  }
}

extern "C" void kernel_launch(void* const* d_in, const int* in_sizes, int n_in,
                              void* d_out, int out_size, void* d_ws, size_t ws_size,
                              hipStream_t stream) {
  // inputs: 0:x 1:ii_w 2:ii_b 3:hi_w 4:hi_b 5:if__w 6:if__b 7:hf_w 8:hf_b
  //         9:ig_w 10:ig_b 11:hg_w 12:hg_b 13:io_w 14:io_b 15:ho_w 16:ho_b
  const float* x = (const float*)d_in[0];
  const float* wx0 = (const float*)d_in[1];
  const float* wx1 = (const float*)d_in[5];
  const float* wx2 = (const float*)d_in[9];
  const float* wx3 = (const float*)d_in[13];
  const float* wh0 = (const float*)d_in[3];
  const float* wh1 = (const float*)d_in[7];
  const float* wh2 = (const float*)d_in[11];
  const float* wh3 = (const float*)d_in[15];
  const float* bx0 = (const float*)d_in[2];
  const float* bx1 = (const float*)d_in[6];
  const float* bx2 = (const float*)d_in[10];
  const float* bx3 = (const float*)d_in[14];
  const float* bh0 = (const float*)d_in[4];
  const float* bh1 = (const float*)d_in[8];
  const float* bh2 = (const float*)d_in[12];
  const float* bh3 = (const float*)d_in[16];

  char* ws = (char*)d_ws;
  unsigned short* WxT = (unsigned short*)(ws + 0);
  unsigned short* WhT = (unsigned short*)(ws + 524288);
  float* bcat = (float*)(ws + 1048576);
  unsigned short* P = (unsigned short*)(ws + 1052672);  // 255*1024*256 bf16

  lstm_prep_w<<<dim3(8, 8, 8), 256, 0, stream>>>(wx0, wx1, wx2, wx3,
                                                 wh0, wh1, wh2, wh3, WxT, WhT);
  lstm_prep_b<<<4, 256, 0, stream>>>(bx0, bx1, bx2, bx3, bh0, bh1, bh2, bh3, bcat);
  lstm_precompute<<<dim3(255, 16), 256, 0, stream>>>(x, WxT, bcat, P);
  lstm_recurrent<<<16, 256, 0, stream>>>(WhT, P, (float*)d_out);
}

// Round 2
// 2600.980 us; speedup vs baseline: 1.2302x; 1.2302x over previous
//
#include <hip/hip_runtime.h>

// LSTM_77893526880768: B=T=F=H=256.  256 independent row-chains, 255 steps.
//
// v2 architecture:
//   prep_w/prep_b: as v1 (transpose weights to bf16 [n][k], fold biases).
//   precompute v2: one WG per t; x[.,t,.] fragments held in registers (x read
//                  once); sweep 16 n-blocks; P written in [t][rg][n][16r] layout.
//   recurrent v2:  64 WGs = 16 row-groups x 4 col-groups. Each wave holds its
//                  4-gate x 16-col weight slab in 128 VGPRs (loaded once).
//                  h exchanged through global Hbuf (double-buffered by parity),
//                  per-step per-rowgroup flag counters (agent scope) sync the
//                  4 col-WGs. c stays in fp32 registers for all 255 steps.
//
// Workspace layout:
//   [0, 16K)        flags   (255*16 ints, zeroed by hipMemsetAsync after precompute;
//   [16K, 16K+256K) Hbuf[2][256][256] bf16        these overlay WxT, dead by then)
//   [0, 512K)       WxT bf16   (live only until precompute finishes)
//   [512K, 1M)      WhT bf16
//   [1M, 1M+4K)     bcat fp32
//   [1M+4K, ...)    P bf16  [t][rg][n][16] = 255*16*1024*16*2 = 133,693,440 B

#define STEPS 255

typedef short bf16x8 __attribute__((ext_vector_type(8)));
typedef short bf16x4 __attribute__((ext_vector_type(4)));
typedef float f32x4  __attribute__((ext_vector_type(4)));

__device__ inline unsigned short f2bf(float f) {
  unsigned int u = __float_as_uint(f);
  unsigned int r = (u + 0x7FFFu + ((u >> 16) & 1u)) >> 16;  // RNE
  return (unsigned short)r;
}
__device__ inline float bf2f(unsigned short s) {
  return __uint_as_float(((unsigned int)s) << 16);
}
__device__ inline float sig_f(float x) {
  float e = exp2f(-1.442695041f * x);
  return __builtin_amdgcn_rcpf(1.0f + e);
}
__device__ inline float tanh_f(float x) {
  float e = exp2f(-2.885390082f * x);
  return 2.0f * __builtin_amdgcn_rcpf(1.0f + e) - 1.0f;
}

// ---------- prep: W transpose (W[k][j] fp32 -> WT[g*256+j][k] bf16) ----------
__global__ __launch_bounds__(256) void lstm_prep_w(
    const float* __restrict__ m0, const float* __restrict__ m1,
    const float* __restrict__ m2, const float* __restrict__ m3,
    const float* __restrict__ m4, const float* __restrict__ m5,
    const float* __restrict__ m6, const float* __restrict__ m7,
    unsigned short* __restrict__ WxT, unsigned short* __restrict__ WhT) {
  const float* mats[8] = {m0, m1, m2, m3, m4, m5, m6, m7};
  int mat = blockIdx.z;
  const float* W = mats[mat];
  unsigned short* out = (mat < 4 ? WxT : WhT) + (size_t)(mat & 3) * 256 * 256;
  int kblk = blockIdx.x * 32, jblk = blockIdx.y * 32;
  __shared__ float tile[32][33];
  int tx = threadIdx.x & 31, ty = threadIdx.x >> 5;
#pragma unroll
  for (int i = 0; i < 4; ++i) {
    int kk = ty + i * 8;
    tile[kk][tx] = W[(size_t)(kblk + kk) * 256 + jblk + tx];
  }
  __syncthreads();
#pragma unroll
  for (int i = 0; i < 4; ++i) {
    int jj = ty + i * 8;
    out[(size_t)(jblk + jj) * 256 + kblk + tx] = f2bf(tile[tx][jj]);
  }
}

// ---------- prep: bias fold ----------
__global__ void lstm_prep_b(
    const float* __restrict__ bx0, const float* __restrict__ bx1,
    const float* __restrict__ bx2, const float* __restrict__ bx3,
    const float* __restrict__ bh0, const float* __restrict__ bh1,
    const float* __restrict__ bh2, const float* __restrict__ bh3,
    float* __restrict__ bcat) {
  const float* bx[4] = {bx0, bx1, bx2, bx3};
  const float* bh[4] = {bh0, bh1, bh2, bh3};
  int i = blockIdx.x * 256 + threadIdx.x;
  int g = i >> 8, j = i & 255;
  bcat[i] = bx[g][j] + bh[g][j];
}

// ---------- precompute v2: one WG per t; x-frags register-resident ----------
// P[t][rg][n][rl] = bcat[n] + sum_k x[rg*16+rl, t, k] * Wx[k, n]
__global__ __launch_bounds__(256, 1) void lstm_precompute(
    const float* __restrict__ x, const unsigned short* __restrict__ WxT,
    const float* __restrict__ bcat, unsigned short* __restrict__ P) {
  int t = blockIdx.x;  // 0..254
  int tid = threadIdx.x;
  int w = tid >> 6, lane = tid & 63, q = lane >> 4, cl = lane & 15;
  int rbase = w * 64;  // wave w owns r in [w*64, w*64+64)

  // x fragments for all 8 k-tiles x 4 r-tiles: B[n=r][k] layout, held in regs
  bf16x8 bfrag[8][4];
#pragma unroll
  for (int kt = 0; kt < 8; ++kt) {
    int k0 = kt * 32 + q * 8;
#pragma unroll
    for (int rt = 0; rt < 4; ++rt) {
      const float* xp = x + (((size_t)(rbase + rt * 16 + cl) * 256 + t) * 256 + k0);
      f32x4 lo = *(const f32x4*)xp;
      f32x4 hi = *(const f32x4*)(xp + 4);
      bf16x8 bv;
      bv[0] = (short)f2bf(lo[0]); bv[1] = (short)f2bf(lo[1]);
      bv[2] = (short)f2bf(lo[2]); bv[3] = (short)f2bf(lo[3]);
      bv[4] = (short)f2bf(hi[0]); bv[5] = (short)f2bf(hi[1]);
      bv[6] = (short)f2bf(hi[2]); bv[7] = (short)f2bf(hi[3]);
      bfrag[kt][rt] = bv;
    }
  }

  for (int nb = 0; nb < 16; ++nb) {
    int nblk = nb * 64;
    f32x4 acc[4][4];  // [mt(n)][rt(r)]
#pragma unroll
    for (int a = 0; a < 4; ++a)
#pragma unroll
      for (int b = 0; b < 4; ++b) acc[a][b] = f32x4{0.f, 0.f, 0.f, 0.f};

#pragma unroll
    for (int kt = 0; kt < 8; ++kt) {
      int k0 = kt * 32 + q * 8;
      bf16x8 afrag[4];
#pragma unroll
      for (int mt = 0; mt < 4; ++mt)
        afrag[mt] = *(const bf16x8*)(WxT + (size_t)(nblk + mt * 16 + cl) * 256 + k0);
#pragma unroll
      for (int mt = 0; mt < 4; ++mt)
#pragma unroll
        for (int rt = 0; rt < 4; ++rt)
          acc[mt][rt] = __builtin_amdgcn_mfma_f32_16x16x32_bf16(
              afrag[mt], bfrag[kt][rt], acc[mt][rt], 0, 0, 0);
    }
    // epilogue: D row (= n) = q*4+reg, col (= r) = cl; store to [t][rg][n][rl]
#pragma unroll
    for (int mt = 0; mt < 4; ++mt) {
#pragma unroll
      for (int reg = 0; reg < 4; ++reg) {
        int n = nblk + mt * 16 + q * 4 + reg;
        float bb = bcat[n];
#pragma unroll
        for (int rt = 0; rt < 4; ++rt) {
          int rg_ = w * 4 + rt;  // = r>>4, rl = cl
          P[(((size_t)t * 16 + rg_) * 1024 + n) * 16 + cl] = f2bf(acc[mt][rt][reg] + bb);
        }
      }
    }
  }
}

// ---------- recurrent v2: 64 WGs, register-resident weights ----------
__global__ __launch_bounds__(256, 1) void lstm_recurrent(
    const unsigned short* __restrict__ WhT, const unsigned short* __restrict__ P,
    unsigned short* __restrict__ Hbuf, int* __restrict__ flags,
    float* __restrict__ out) {
  int tid = threadIdx.x;
  int w = tid >> 6, lane = tid & 63, q = lane >> 4, cl = lane & 15;
  int rg = blockIdx.x;            // row group: rows [rg*16, rg*16+16)
  int cg = blockIdx.y;            // col group
  int r0 = rg * 16;
  int j0 = cg * 64 + w * 16;      // this wave's 16 hidden cols

  // 4 gates x 16 cols x 256 k of WhT -> 32 bf16x8 = 128 VGPRs, loaded once
  bf16x8 wreg[4][8];
#pragma unroll
  for (int g = 0; g < 4; ++g)
#pragma unroll
    for (int kt = 0; kt < 8; ++kt)
      wreg[g][kt] = *(const bf16x8*)(WhT + (size_t)(g * 256 + j0 + cl) * 256 + kt * 32 + q * 8);

  float creg[4] = {0.f, 0.f, 0.f, 0.f};  // c[r = r0+q*4+e][j = j0+cl]
  unsigned short* H0 = Hbuf;
  unsigned short* H1 = Hbuf + 65536;

  for (int t = 0; t < STEPS; ++t) {
    // P prefetch (no dependence on peers) — issued before the flag spin
    const unsigned short* Pt = P + ((size_t)t * 16 + rg) * 1024 * 16;
    bf16x4 pv[4];
#pragma unroll
    for (int g = 0; g < 4; ++g)
      pv[g] = *(const bf16x4*)(Pt + (size_t)(g * 256 + j0 + cl) * 16 + q * 4);

    if (t > 0) {
      if (tid == 0) {
        const int* fp = flags + t * 16 + rg;
        while (__hip_atomic_load(fp, __ATOMIC_ACQUIRE, __HIP_MEMORY_SCOPE_AGENT) < 4)
          __builtin_amdgcn_s_sleep(1);
      }
      __syncthreads();
    }

    // A-frags: h_t rows (A[m=cl][k=q*8+j])
    const unsigned short* Hr = ((t & 1) ? H1 : H0) + (size_t)(r0 + cl) * 256;
    bf16x8 afrag[8];
#pragma unroll
    for (int kt = 0; kt < 8; ++kt)
      afrag[kt] = *(const bf16x8*)(Hr + kt * 32 + q * 8);

    f32x4 acc[4];
#pragma unroll
    for (int g = 0; g < 4; ++g) acc[g] = f32x4{0.f, 0.f, 0.f, 0.f};
#pragma unroll
    for (int kt = 0; kt < 8; ++kt)
#pragma unroll
      for (int g = 0; g < 4; ++g)
        acc[g] = __builtin_amdgcn_mfma_f32_16x16x32_bf16(afrag[kt], wreg[g][kt], acc[g], 0, 0, 0);

    unsigned short* Hw = ((t & 1) ? H0 : H1);
    bool last = (t == STEPS - 1);
#pragma unroll
    for (int e = 0; e < 4; ++e) {
      float pi = acc[0][e] + bf2f((unsigned short)pv[0][e]);
      float pf = acc[1][e] + bf2f((unsigned short)pv[1][e]);
      float pg = acc[2][e] + bf2f((unsigned short)pv[2][e]);
      float po = acc[3][e] + bf2f((unsigned short)pv[3][e]);
      float ig = sig_f(pi), fg = sig_f(pf), gg = tanh_f(pg), og = sig_f(po);
      float cn = fg * creg[e] + ig * gg;
      creg[e] = cn;
      float hn = og * tanh_f(cn);
      int r = r0 + q * 4 + e, j = j0 + cl;
      if (!last) {
        Hw[(size_t)r * 256 + j] = f2bf(hn);
      } else {
        out[(size_t)r * 256 + j] = hn;
        out[65536 + (size_t)r * 256 + j] = cn;
      }
    }

    if (!last) {
      __threadfence();     // each thread drains its h stores to agent scope
      __syncthreads();
      if (tid == 0)
        __hip_atomic_fetch_add(flags + (t + 1) * 16 + rg, 1,
                               __ATOMIC_RELEASE, __HIP_MEMORY_SCOPE_AGENT);
    }
  }
}

extern "C" void kernel_launch(void* const* d_in, const int* in_sizes, int n_in,
                              void* d_out, int out_size, void* d_ws, size_t ws_size,
                              hipStream_t stream) {
  const float* x = (const float*)d_in[0];
  const float* wx0 = (const float*)d_in[1];
  const float* wx1 = (const float*)d_in[5];
  const float* wx2 = (const float*)d_in[9];
  const float* wx3 = (const float*)d_in[13];
  const float* wh0 = (const float*)d_in[3];
  const float* wh1 = (const float*)d_in[7];
  const float* wh2 = (const float*)d_in[11];
  const float* wh3 = (const float*)d_in[15];
  const float* bx0 = (const float*)d_in[2];
  const float* bx1 = (const float*)d_in[6];
  const float* bx2 = (const float*)d_in[10];
  const float* bx3 = (const float*)d_in[14];
  const float* bh0 = (const float*)d_in[4];
  const float* bh1 = (const float*)d_in[8];
  const float* bh2 = (const float*)d_in[12];
  const float* bh3 = (const float*)d_in[16];

  char* ws = (char*)d_ws;
  unsigned short* WxT = (unsigned short*)(ws + 0);        // dead after precompute
  unsigned short* WhT = (unsigned short*)(ws + 524288);
  float* bcat = (float*)(ws + 1048576);
  unsigned short* P = (unsigned short*)(ws + 1052672);    // [t][rg][n][16] bf16
  int* flags = (int*)(ws + 0);                            // overlays WxT
  unsigned short* Hbuf = (unsigned short*)(ws + 16384);   // [2][256][256] bf16

  lstm_prep_w<<<dim3(8, 8, 8), 256, 0, stream>>>(wx0, wx1, wx2, wx3,
                                                 wh0, wh1, wh2, wh3, WxT, WhT);
  lstm_prep_b<<<4, 256, 0, stream>>>(bx0, bx1, bx2, bx3, bh0, bh1, bh2, bh3, bcat);
  lstm_precompute<<<255, 256, 0, stream>>>(x, WxT, bcat, P);
  // zero flags (16 KB) + Hbuf (256 KB) — region overlays WxT, which is dead now
  hipMemsetAsync(ws, 0, 16384 + 262144, stream);
  lstm_recurrent<<<dim3(16, 4), 256, 0, stream>>>(WhT, P, Hbuf, flags, (float*)d_out);
}

// Round 4
// 2313.559 us; speedup vs baseline: 1.3831x; 1.1242x over previous
//
#include <hip/hip_runtime.h>

// LSTM_77893526880768: B=T=F=H=256.  256 independent row-chains, 255 steps.
//
// v4 recurrent architecture:
//   64 WGs = 16 row-groups x 4 col-groups, 256 threads (4 waves).
//   Wave w = gate w: holds Wh[gate w][cg*64 .. +64 cols][all 256 k] in 128 VGPRs,
//   loaded ONCE through a volatile pointer (defeats the invariant-load remat
//   that killed v2 perf: VGPR_Count=108 proved weights were re-streamed).
//   Gate recombination (i,f,g,o -> c,h) via LDS tile; c in fp32 registers.
//
//   h exchange: v2's HW-PROVEN release/acquire protocol (v3's relaxed-only
//   scheme failed: vmcnt-ack of sc1 stores does not imply IC visibility, so
//   the flag could beat the h data to the coherence point — LLVM's agent
//   release emits buffer_wbl2 sc1 for exactly this reason):
//     producer: plain h stores -> __threadfence (buffer_wbl2 sc1 + waitcnt)
//               -> __syncthreads -> tid0 fetch_add RELEASE flags[t+1][rg]
//     consumer: tid0 polls flags[t][rg] with ACQUIRE loads (buffer_inv sc1)
//               -> __syncthreads -> plain h loads (refill from IC, L1-shared
//               across the 4 waves reading the same 8 KB h-slab)
//   P prefetch for step t is issued BEFORE the poll (register-resident, so
//   the L2 invalidates cannot hurt it).
//
// Workspace layout:
//   [0, 16K)        flags int[255][16] (memset 0 after precompute)
//   [16K, 16K+256K) Hbuf bf16[2][256][256]  (h double buffer; buf0 = h_0 = 0)
//                   (both overlay WxT, which is dead after precompute)
//   [0, 512K)       WxT bf16   (live only until precompute finishes)
//   [512K, 1M)      WhT bf16
//   [1M, 1M+4K)     bcat fp32
//   [1M+4K, ...)    P bf16  [t][rg][n][16] = 133,693,440 B

#define STEPS 255

typedef short bf16x8 __attribute__((ext_vector_type(8)));
typedef short bf16x4 __attribute__((ext_vector_type(4)));
typedef float f32x4  __attribute__((ext_vector_type(4)));

__device__ inline unsigned short f2bf(float f) {
  unsigned int u = __float_as_uint(f);
  unsigned int r = (u + 0x7FFFu + ((u >> 16) & 1u)) >> 16;  // RNE
  return (unsigned short)r;
}
__device__ inline float bf2f(unsigned short s) {
  return __uint_as_float(((unsigned int)s) << 16);
}
__device__ inline float sig_f(float x) {
  float e = exp2f(-1.442695041f * x);
  return __builtin_amdgcn_rcpf(1.0f + e);
}
__device__ inline float tanh_f(float x) {
  float e = exp2f(-2.885390082f * x);
  return 2.0f * __builtin_amdgcn_rcpf(1.0f + e) - 1.0f;
}

// ---------- prep: W transpose (W[k][j] fp32 -> WT[g*256+j][k] bf16) ----------
__global__ __launch_bounds__(256) void lstm_prep_w(
    const float* __restrict__ m0, const float* __restrict__ m1,
    const float* __restrict__ m2, const float* __restrict__ m3,
    const float* __restrict__ m4, const float* __restrict__ m5,
    const float* __restrict__ m6, const float* __restrict__ m7,
    unsigned short* __restrict__ WxT, unsigned short* __restrict__ WhT) {
  const float* mats[8] = {m0, m1, m2, m3, m4, m5, m6, m7};
  int mat = blockIdx.z;
  const float* W = mats[mat];
  unsigned short* out = (mat < 4 ? WxT : WhT) + (size_t)(mat & 3) * 256 * 256;
  int kblk = blockIdx.x * 32, jblk = blockIdx.y * 32;
  __shared__ float tile[32][33];
  int tx = threadIdx.x & 31, ty = threadIdx.x >> 5;
#pragma unroll
  for (int i = 0; i < 4; ++i) {
    int kk = ty + i * 8;
    tile[kk][tx] = W[(size_t)(kblk + kk) * 256 + jblk + tx];
  }
  __syncthreads();
#pragma unroll
  for (int i = 0; i < 4; ++i) {
    int jj = ty + i * 8;
    out[(size_t)(jblk + jj) * 256 + kblk + tx] = f2bf(tile[tx][jj]);
  }
}

// ---------- prep: bias fold ----------
__global__ void lstm_prep_b(
    const float* __restrict__ bx0, const float* __restrict__ bx1,
    const float* __restrict__ bx2, const float* __restrict__ bx3,
    const float* __restrict__ bh0, const float* __restrict__ bh1,
    const float* __restrict__ bh2, const float* __restrict__ bh3,
    float* __restrict__ bcat) {
  const float* bx[4] = {bx0, bx1, bx2, bx3};
  const float* bh[4] = {bh0, bh1, bh2, bh3};
  int i = blockIdx.x * 256 + threadIdx.x;
  int g = i >> 8, j = i & 255;
  bcat[i] = bx[g][j] + bh[g][j];
}

// ---------- precompute: P[t][rg][n][rl] = bcat[n] + sum_k x[r,t,k] Wx[k,n] ----------
__global__ __launch_bounds__(256, 1) void lstm_precompute(
    const float* __restrict__ x, const unsigned short* __restrict__ WxT,
    const float* __restrict__ bcat, unsigned short* __restrict__ P) {
  int t = blockIdx.x;
  int tid = threadIdx.x;
  int w = tid >> 6, lane = tid & 63, q = lane >> 4, cl = lane & 15;
  int rbase = w * 64;

  bf16x8 bfrag[8][4];
#pragma unroll
  for (int kt = 0; kt < 8; ++kt) {
    int k0 = kt * 32 + q * 8;
#pragma unroll
    for (int rt = 0; rt < 4; ++rt) {
      const float* xp = x + (((size_t)(rbase + rt * 16 + cl) * 256 + t) * 256 + k0);
      f32x4 lo = *(const f32x4*)xp;
      f32x4 hi = *(const f32x4*)(xp + 4);
      bf16x8 bv;
      bv[0] = (short)f2bf(lo[0]); bv[1] = (short)f2bf(lo[1]);
      bv[2] = (short)f2bf(lo[2]); bv[3] = (short)f2bf(lo[3]);
      bv[4] = (short)f2bf(hi[0]); bv[5] = (short)f2bf(hi[1]);
      bv[6] = (short)f2bf(hi[2]); bv[7] = (short)f2bf(hi[3]);
      bfrag[kt][rt] = bv;
    }
  }

  for (int nb = 0; nb < 16; ++nb) {
    int nblk = nb * 64;
    f32x4 acc[4][4];
#pragma unroll
    for (int a = 0; a < 4; ++a)
#pragma unroll
      for (int b = 0; b < 4; ++b) acc[a][b] = f32x4{0.f, 0.f, 0.f, 0.f};

#pragma unroll
    for (int kt = 0; kt < 8; ++kt) {
      int k0 = kt * 32 + q * 8;
      bf16x8 afrag[4];
#pragma unroll
      for (int mt = 0; mt < 4; ++mt)
        afrag[mt] = *(const bf16x8*)(WxT + (size_t)(nblk + mt * 16 + cl) * 256 + k0);
#pragma unroll
      for (int mt = 0; mt < 4; ++mt)
#pragma unroll
        for (int rt = 0; rt < 4; ++rt)
          acc[mt][rt] = __builtin_amdgcn_mfma_f32_16x16x32_bf16(
              afrag[mt], bfrag[kt][rt], acc[mt][rt], 0, 0, 0);
    }
#pragma unroll
    for (int mt = 0; mt < 4; ++mt) {
#pragma unroll
      for (int reg = 0; reg < 4; ++reg) {
        int n = nblk + mt * 16 + q * 4 + reg;
        float bb = bcat[n];
#pragma unroll
        for (int rt = 0; rt < 4; ++rt) {
          int rg_ = w * 4 + rt;
          P[(((size_t)t * 16 + rg_) * 1024 + n) * 16 + cl] = f2bf(acc[mt][rt][reg] + bb);
        }
      }
    }
  }
}

// ---------- recurrent v4 ----------
__global__ __launch_bounds__(256, 1) void lstm_recurrent(
    const unsigned short* WhT,  // no __restrict__: loaded via volatile below
    const unsigned short* __restrict__ P,
    unsigned short* Hbuf, int* flags,
    float* __restrict__ out) {
  __shared__ float gates_lds[4][16][65];  // [gate][r][j] +pad
  int tid = threadIdx.x;
  int w = tid >> 6, lane = tid & 63, q = lane >> 4, cl = lane & 15;
  int rg = blockIdx.x;  // rows [rg*16, rg*16+16)
  int cg = blockIdx.y;  // cols [cg*64, cg*64+64)
  int r0 = rg * 16;
  int jcol = cg * 64 + w * 16 + cl;  // elementwise column owned by this lane

  // ---- weights: gate w, 64 cols, 256 k -> 32 x bf16x8 = 128 VGPRs, loaded once.
  // volatile: forbid sinking these invariant loads into the t-loop.
  bf16x8 wreg[4][8];  // [jt (16-col tile)][kt]
  {
    const volatile bf16x8* wb = (const volatile bf16x8*)WhT;
#pragma unroll
    for (int jt = 0; jt < 4; ++jt)
#pragma unroll
      for (int kt = 0; kt < 8; ++kt)
        wreg[jt][kt] = wb[(size_t)(w * 256 + cg * 64 + jt * 16 + cl) * 32 + kt * 4 + q];
  }

  float creg[4] = {0.f, 0.f, 0.f, 0.f};  // c[r=r0+q*4+e][j=jcol]
  unsigned short* H0 = Hbuf;             // [256][256] bf16
  unsigned short* H1 = Hbuf + 65536;

  for (int t = 0; t < STEPS; ++t) {
    // P prefetch (independent of peers) before the flag wait — lands in regs,
    // so the poll's buffer_inv cannot hurt it.
    const unsigned short* Pt = P + ((size_t)t * 16 + rg) * 1024 * 16;
    bf16x4 pv[4];
#pragma unroll
    for (int g = 0; g < 4; ++g)
      pv[g] = *(const bf16x4*)(Pt + (size_t)(g * 256 + jcol) * 16 + q * 4);

    if (t > 0) {
      if (tid == 0) {
        const int* fp = flags + t * 16 + rg;  // == 4 when all peers finished t-1
        while (__hip_atomic_load(fp, __ATOMIC_ACQUIRE, __HIP_MEMORY_SCOPE_AGENT) < 4)
          __builtin_amdgcn_s_sleep(1);
      }
      __syncthreads();
    }

    // ---- A-frags: h_t rows (A[m=cl][k=q*8+j]); plain loads, post-acquire
    const unsigned short* Hr = ((t & 1) ? H1 : H0) + (size_t)(r0 + cl) * 256;
    bf16x8 afrag[8];
#pragma unroll
    for (int kt = 0; kt < 8; ++kt)
      afrag[kt] = *(const bf16x8*)(Hr + kt * 32 + q * 8);

    // ---- MFMA: gate w, rows r0..r0+16, cols cg*64..+64
    f32x4 acc[4];
#pragma unroll
    for (int jt = 0; jt < 4; ++jt) acc[jt] = f32x4{0.f, 0.f, 0.f, 0.f};
#pragma unroll
    for (int kt = 0; kt < 8; ++kt)
#pragma unroll
      for (int jt = 0; jt < 4; ++jt)
        acc[jt] = __builtin_amdgcn_mfma_f32_16x16x32_bf16(afrag[kt], wreg[jt][kt], acc[jt], 0, 0, 0);

    // ---- redistribute gates through LDS: wave w wrote gate w; each wave then
    //      handles elementwise for cols [w*16, w*16+16) of this WG's 64.
#pragma unroll
    for (int jt = 0; jt < 4; ++jt)
#pragma unroll
      for (int e = 0; e < 4; ++e)
        gates_lds[w][q * 4 + e][jt * 16 + cl] = acc[jt][e];
    __syncthreads();

    unsigned short* Hw = ((t & 1) ? H0 : H1);
    bool last = (t == STEPS - 1);
#pragma unroll
    for (int e = 0; e < 4; ++e) {
      int rr = q * 4 + e;
      float pi = gates_lds[0][rr][w * 16 + cl] + bf2f((unsigned short)pv[0][e]);
      float pf = gates_lds[1][rr][w * 16 + cl] + bf2f((unsigned short)pv[1][e]);
      float pg = gates_lds[2][rr][w * 16 + cl] + bf2f((unsigned short)pv[2][e]);
      float po = gates_lds[3][rr][w * 16 + cl] + bf2f((unsigned short)pv[3][e]);
      float ig = sig_f(pi), fg = sig_f(pf), gg = tanh_f(pg), og = sig_f(po);
      float cn = fg * creg[e] + ig * gg;
      creg[e] = cn;
      float hn = og * tanh_f(cn);
      int r = r0 + rr;
      if (!last) {
        Hw[(size_t)r * 256 + jcol] = f2bf(hn);  // plain store (v2-proven path)
      } else {
        out[(size_t)r * 256 + jcol] = hn;
        out[65536 + (size_t)r * 256 + jcol] = cn;
      }
    }

    if (!last) {
      // v2-proven release sequence: wbl2+waitcnt per thread, then one RMW.
      __threadfence();
      __syncthreads();  // also protects gates_lds for the next step
      if (tid == 0)
        __hip_atomic_fetch_add(flags + (t + 1) * 16 + rg, 1,
                               __ATOMIC_RELEASE, __HIP_MEMORY_SCOPE_AGENT);
    }
  }
}

extern "C" void kernel_launch(void* const* d_in, const int* in_sizes, int n_in,
                              void* d_out, int out_size, void* d_ws, size_t ws_size,
                              hipStream_t stream) {
  const float* x = (const float*)d_in[0];
  const float* wx0 = (const float*)d_in[1];
  const float* wx1 = (const float*)d_in[5];
  const float* wx2 = (const float*)d_in[9];
  const float* wx3 = (const float*)d_in[13];
  const float* wh0 = (const float*)d_in[3];
  const float* wh1 = (const float*)d_in[7];
  const float* wh2 = (const float*)d_in[11];
  const float* wh3 = (const float*)d_in[15];
  const float* bx0 = (const float*)d_in[2];
  const float* bx1 = (const float*)d_in[6];
  const float* bx2 = (const float*)d_in[10];
  const float* bx3 = (const float*)d_in[14];
  const float* bh0 = (const float*)d_in[4];
  const float* bh1 = (const float*)d_in[8];
  const float* bh2 = (const float*)d_in[12];
  const float* bh3 = (const float*)d_in[16];

  char* ws = (char*)d_ws;
  unsigned short* WxT = (unsigned short*)(ws + 0);          // dead after precompute
  unsigned short* WhT = (unsigned short*)(ws + 524288);
  float* bcat = (float*)(ws + 1048576);
  unsigned short* P = (unsigned short*)(ws + 1052672);      // [t][rg][n][16] bf16
  int* flags = (int*)(ws + 0);                              // overlays WxT
  unsigned short* Hbuf = (unsigned short*)(ws + 16384);     // [2][256][256] bf16

  lstm_prep_w<<<dim3(8, 8, 8), 256, 0, stream>>>(wx0, wx1, wx2, wx3,
                                                 wh0, wh1, wh2, wh3, WxT, WhT);
  lstm_prep_b<<<4, 256, 0, stream>>>(bx0, bx1, bx2, bx3, bh0, bh1, bh2, bh3, bcat);
  lstm_precompute<<<255, 256, 0, stream>>>(x, WxT, bcat, P);
  hipMemsetAsync(ws, 0, 16384 + 262144, stream);  // flags + Hbuf (h_0 = 0)
  lstm_recurrent<<<dim3(16, 4), 256, 0, stream>>>(WhT, P, Hbuf, flags, (float*)d_out);
}